// Round 11
// baseline (365.724 us; speedup 1.0000x reference)
//
#include <hip/hip_runtime.h>
#include <cstdint>
#include <cstddef>

#define BETA 5.5f
#define ALPHA 0.5f

constexpr int D   = 512;     // feature dim
constexpr int NB  = 4096;    // queries
constexpr int NK  = 16384;   // keys
constexpr int BQ  = 64;      // query tile per block
constexpr int BN  = 64;      // key chunk
constexpr int NSPLIT = 8;    // per-XCD KnF+KnT slice = 4MB = L2
constexpr int NRANGE = NK / NSPLIT;   // 2048
constexpr int CHUNKS = NRANGE / BN;   // 32
constexpr int KROW = D + 8;           // norm_k LDS row pad
constexpr int PROW = BN + 8;          // padded P row: 72
// KnF fragment-major (32x32x16 A-op): elem off =
//   gchunk*32768 + nh*16384 + kh*8192 + ks*512 + lane*8
//   (gchunk = 64-key chunk, nh = 32-key group, kh = D-half, ks = 16-d step)
constexpr int KFCH = 32768;

typedef __attribute__((ext_vector_type(8)))  short    short8;
typedef __attribute__((ext_vector_type(4)))  float    floatx4;
typedef __attribute__((ext_vector_type(16))) float    floatx16;
typedef __attribute__((ext_vector_type(4)))  uint32_t uint4v;
typedef __attribute__((ext_vector_type(2)))  uint32_t uint2v;

__device__ inline uint32_t f2bf1(float f) {
  union { float f; uint32_t u; } v; v.f = f;
  return (v.u + 0x7FFFu + ((v.u >> 16) & 1u)) >> 16;   // RNE
}
__device__ inline uint32_t pack2(float a, float b) {
  return f2bf1(a) | (f2bf1(b) << 16);
}

// ---------------- normalize Q -> Qn (bf16), and init out = Q ----------------
__global__ void norm_q_kernel(const float* __restrict__ q,
                              float* __restrict__ out,
                              unsigned short* __restrict__ Qn) {
  const int wave = threadIdx.x >> 6, lane = threadIdx.x & 63;
  const int row = blockIdx.x * 4 + wave;
  const float4* qr = (const float4*)(q + (size_t)row * D);
  float4 a = qr[lane * 2];
  float4 b = qr[lane * 2 + 1];
  float ss = a.x*a.x + a.y*a.y + a.z*a.z + a.w*a.w
           + b.x*b.x + b.y*b.y + b.z*b.z + b.w*b.w;
#pragma unroll
  for (int m = 32; m >= 1; m >>= 1) ss += __shfl_xor(ss, m, 64);
  const float sc = 1.0f / fmaxf(sqrtf(ss), 1e-12f);
  float4* orow = (float4*)(out + (size_t)row * D);
  orow[lane * 2]     = a;
  orow[lane * 2 + 1] = b;
  uint4v w;
  w.x = pack2(a.x*sc, a.y*sc); w.y = pack2(a.z*sc, a.w*sc);
  w.z = pack2(b.x*sc, b.y*sc); w.w = pack2(b.z*sc, b.w*sc);
  *(uint4v*)(Qn + (size_t)row * D + lane * 8) = w;
}

// -- normalize K -> KnF (32x32-A fragment-major) + KnT (transposed) ----------
__global__ void norm_k_kernel(const float* __restrict__ k,
                              unsigned short* __restrict__ KnF,
                              unsigned short* __restrict__ KnT) {
  __shared__ unsigned short tile[64 * KROW];
  const int wave = threadIdx.x >> 6, lane = threadIdx.x & 63;
  const int l31 = lane & 31, half = lane >> 5;
  const int n0 = blockIdx.x * 64;
#pragma unroll
  for (int i = 0; i < 4; ++i) {
    const int rl = wave * 4 + i;
    const int n  = n0 + rl;
    const float4* kr = (const float4*)(k + (size_t)n * D);
    float4 a = kr[lane * 2], b = kr[lane * 2 + 1];
    float ss = a.x*a.x + a.y*a.y + a.z*a.z + a.w*a.w
             + b.x*b.x + b.y*b.y + b.z*b.z + b.w*b.w;
#pragma unroll
    for (int m = 32; m >= 1; m >>= 1) ss += __shfl_xor(ss, m, 64);
    const float sc = 1.0f / fmaxf(sqrtf(ss), 1e-12f);
    uint4v w;
    w.x = pack2(a.x*sc, a.y*sc); w.y = pack2(a.z*sc, a.w*sc);
    w.z = pack2(b.x*sc, b.y*sc); w.w = pack2(b.z*sc, b.w*sc);
    *(uint4v*)&tile[rl * KROW + lane * 8] = w;
  }
  __syncthreads();
  // KnT: [d][n]
  {
    const int dsub = threadIdx.x >> 3;        // 0..127
    const int nl   = (threadIdx.x & 7) * 8;   // 0..56
#pragma unroll
    for (int iter = 0; iter < 4; ++iter) {
      const int d = iter * 128 + dsub;
      uint4v w;
      w.x = (uint32_t)tile[(nl+0)*KROW + d] | ((uint32_t)tile[(nl+1)*KROW + d] << 16);
      w.y = (uint32_t)tile[(nl+2)*KROW + d] | ((uint32_t)tile[(nl+3)*KROW + d] << 16);
      w.z = (uint32_t)tile[(nl+4)*KROW + d] | ((uint32_t)tile[(nl+5)*KROW + d] << 16);
      w.w = (uint32_t)tile[(nl+6)*KROW + d] | ((uint32_t)tile[(nl+7)*KROW + d] << 16);
      *(uint4v*)(KnT + (size_t)d * NK + n0 + nl) = w;
    }
  }
  // KnF: A-frag order for mfma_32x32x16 (A[m=l31][k=half*8+j]).
  // wave w -> nt = w&1, kh = (w>>1)&1, kp = w>>2 (ks = kp*4..+3)
  {
    const int nt = wave & 1, kh = (wave >> 1) & 1, kp = wave >> 2;
    unsigned short* dst = KnF + (size_t)blockIdx.x * KFCH
                        + nt * 16384 + kh * 8192 + lane * 8;
#pragma unroll
    for (int i = 0; i < 4; ++i) {
      const int ks = kp * 4 + i;
      uint4v v = *(const uint4v*)&tile[(nt*32 + l31) * KROW
                                       + kh*256 + ks*16 + half*8];
      *(uint4v*)(dst + ks * 512) = v;
    }
  }
}

// ---------------- fused: S = Qn Kn^T chunk, P = exp, O += P Kn --------------
// GEMM1: 32x32x16, A streamed DIRECTLY from KnF global (4-deep ring, zero LDS
// -- each A-byte crosses L1 once; qt-partner wave hits L1). kh D-split with
// Sred reduction (R7-verified). GEMM2: 16x16x32 from P_lds + ktf (R5/R10-
// verified). LDS = Sred 16KB + P 9KB only. 2 barriers/chunk, atomic epilogue.
__global__ __launch_bounds__(512, 2) void fused_kernel(
    const unsigned short* __restrict__ Qn,
    const unsigned short* __restrict__ KnF,
    const unsigned short* __restrict__ KnT,
    float* __restrict__ out) {
  __shared__ float Sred[4][32 * 32];               // 16384 B
  __shared__ unsigned short P_lds[BQ * PROW];      //  9216 B   (25.6 KB)

  const int tid  = threadIdx.x;
  const int wave = tid >> 6, lane = tid & 63;
  const int l15  = lane & 15, quad = lane >> 4;
  const int l31  = lane & 31, half = lane >> 5;
  const int nsplit = blockIdx.x & (NSPLIT - 1);
  const int qtile  = blockIdx.x >> 3;           // 0..63
  const int q0     = qtile * BQ;
  const int nbase  = nsplit * NRANGE;
  // GEMM1 roles: S^T tile (nh = key 32-group, qt = q 32-group), D-half kh
  const int nh = wave & 1, qt = (wave >> 1) & 1, kh = wave >> 2;
  const int g1tile = nh * 2 + qt;

  // GEMM1 B-frags (Q): B[k=16][n=32q], n=l31, k=half*8+j; 16 ks (64 VGPR)
  short8 qfB[16];
  {
    const unsigned short* qrow = Qn + (size_t)(q0 + qt*32 + l31) * D
                                 + kh * 256 + half * 8;
#pragma unroll
    for (int ks = 0; ks < 16; ++ks) qfB[ks] = *(const short8*)(qrow + ks * 16);
  }

  floatx4 oacc[4][4] = {};   // wave's 64q x 64d O slice (d cols wave*64..+63)
  short8 ktf[2][4];          // GEMM2 B-frags (32 VGPR), single-buffered
  short8 af[4];              // GEMM1 A-frag ring (32 VGPR)

  const unsigned short* pA0 = KnF + (size_t)(nsplit * CHUNKS) * KFCH
                            + nh * 16384 + kh * 8192 + lane * 8;
  const unsigned short* ktrow = KnT + (size_t)(wave*64 + l15) * NK + nbase + quad*8;

  // prologue: ktf(0), af ring = chunk 0 frags 0..3
#pragma unroll
  for (int kb2 = 0; kb2 < 2; ++kb2)
#pragma unroll
    for (int td = 0; td < 4; ++td)
      ktf[kb2][td] = *(const short8*)(ktrow + (size_t)td*16*NK + kb2*32);
#pragma unroll
  for (int g = 0; g < 4; ++g) af[g] = *(const short8*)(pA0 + g * 512);

#pragma unroll 1
  for (int c = 0; c < CHUNKS; ++c) {
    const int cn = (c + 1 < CHUNKS) ? c + 1 : c;
    const unsigned short* pAc = pA0 + (size_t)c  * KFCH;
    const unsigned short* pAn = pA0 + (size_t)cn * KFCH;

    // ---- GEMM1: A from global ring, B = qfB regs. 16 MFMA(32x32x16).
    floatx16 s = {};
#pragma unroll
    for (int ks = 0; ks < 16; ++ks) {
      short8 a = af[ks & 3];
      const int pk = ks + 4;
      const unsigned short* fp = (pk < 16) ? (pAc + pk * 512)
                                           : (pAn + (pk - 16) * 512);
      af[ks & 3] = *(const short8*)fp;
      s = __builtin_amdgcn_mfma_f32_32x32x16_bf16(a, qfB[ks], s, 0, 0, 0);
    }

    if (kh == 1) {                      // export partial S (lane-symmetric)
      float* sr = &Sred[g1tile][lane * 16];
#pragma unroll
      for (int g = 0; g < 4; ++g) {
        float4 v = { s[4*g], s[4*g+1], s[4*g+2], s[4*g+3] };
        ((float4*)sr)[g] = v;
      }
    }
    __syncthreads();   // bar-A: Sred visible

    if (kh == 0) {                      // reduce, exp, pack, write P
      const float* sr = &Sred[g1tile][lane * 16];
      const int q = qt * 32 + l31;
#pragma unroll
      for (int g = 0; g < 4; ++g) {
        float4 r = ((const float4*)sr)[g];
        float e0 = __expf(BETA * (s[4*g+0] + r.x - 1.f));
        float e1 = __expf(BETA * (s[4*g+1] + r.y - 1.f));
        float e2 = __expf(BETA * (s[4*g+2] + r.z - 1.f));
        float e3 = __expf(BETA * (s[4*g+3] + r.w - 1.f));
        uint2v w; w.x = pack2(e0, e1); w.y = pack2(e2, e3);
        // keys for regs 4g..4g+3: nh*32 + g*8 + half*4 + {0..3}
        *(uint2v*)&P_lds[q * PROW + nh*32 + g*8 + half*4] = w;
      }
    }
    __syncthreads();   // bar-B: P(c) visible

    // ---- GEMM2: O += P (LDS, A-op) * ktf (regs, B-op)  [16x16x32]
#pragma unroll
    for (int kb2 = 0; kb2 < 2; ++kb2) {
      short8 pf[4];
#pragma unroll
      for (int tr = 0; tr < 4; ++tr)
        pf[tr] = *(const short8*)&P_lds[(tr*16 + l15) * PROW + kb2*32 + quad*8];
#pragma unroll
      for (int td = 0; td < 4; ++td)
#pragma unroll
        for (int tr = 0; tr < 4; ++tr)
          oacc[tr][td] = __builtin_amdgcn_mfma_f32_16x16x32_bf16(
              pf[tr], ktf[kb2][td], oacc[tr][td], 0, 0, 0);
    }

    // ---- ktf for next chunk (drained by bar-A(c+1), ~GEMM1 away)
#pragma unroll
    for (int kb2 = 0; kb2 < 2; ++kb2)
#pragma unroll
      for (int td = 0; td < 4; ++td)
        ktf[kb2][td] = *(const short8*)(ktrow + (size_t)td*16*NK + cn*BN + kb2*32);
  }

  // ---- epilogue: out += ALPHA * O (out pre-init to Q; atomics L2-coalesce)
  const int colbase = wave * 64 + l15;
#pragma unroll
  for (int tr = 0; tr < 4; ++tr)
#pragma unroll
    for (int td = 0; td < 4; ++td)
#pragma unroll
      for (int r = 0; r < 4; ++r)
        atomicAdd(out + (size_t)(q0 + tr*16 + quad*4 + r) * D + colbase + td*16,
                  ALPHA * oacc[tr][td][r]);
}

extern "C" void kernel_launch(void* const* d_in, const int* in_sizes, int n_in,
                              void* d_out, int out_size, void* d_ws, size_t ws_size,
                              hipStream_t stream) {
  (void)in_sizes; (void)n_in; (void)out_size; (void)ws_size;
  const float* q = (const float*)d_in[0];
  const float* k = (const float*)d_in[1];
  float* out = (float*)d_out;
  unsigned short* Qn  = (unsigned short*)d_ws;          //  4 MB
  unsigned short* KnF = Qn + (size_t)NB * D;            // 16 MB
  unsigned short* KnT = KnF + (size_t)NK * D;           // 16 MB  (total 36 MB)

  hipLaunchKernelGGL(norm_q_kernel, dim3(NB / 4),  dim3(256),  0, stream, q, out, Qn);
  hipLaunchKernelGGL(norm_k_kernel, dim3(NK / 64), dim3(1024), 0, stream, k, KnF, KnT);
  hipLaunchKernelGGL(fused_kernel, dim3((NB / BQ) * NSPLIT), dim3(512), 0, stream,
                     Qn, KnF, KnT, out);
}

// Round 12
// 331.029 us; speedup vs baseline: 1.1048x; 1.1048x over previous
//
#include <hip/hip_runtime.h>
#include <cstdint>
#include <cstddef>

#define BETA 5.5f
#define ALPHA 0.5f

constexpr int D   = 512;     // feature dim
constexpr int NB  = 4096;    // queries
constexpr int NK  = 16384;   // keys
constexpr int BQ  = 64;      // query tile per block
constexpr int BN  = 64;      // key chunk
constexpr int NSPLIT = 4;
constexpr int NRANGE = NK / NSPLIT;   // 4096
constexpr int CHUNKS = NRANGE / BN;   // 64
constexpr int KROW = D + 8;           // padded LDS row (bf16)
constexpr int PROW = BN + 8;          // padded P row: 72

typedef __attribute__((ext_vector_type(8)))  short    short8;
typedef __attribute__((ext_vector_type(4)))  float    floatx4;
typedef __attribute__((ext_vector_type(16))) float    floatx16;
typedef __attribute__((ext_vector_type(4)))  uint32_t uint4v;
typedef __attribute__((ext_vector_type(2)))  uint32_t uint2v;

__device__ inline uint32_t f2bf1(float f) {
  union { float f; uint32_t u; } v; v.f = f;
  return (v.u + 0x7FFFu + ((v.u >> 16) & 1u)) >> 16;   // RNE
}
__device__ inline uint32_t pack2(float a, float b) {
  return f2bf1(a) | (f2bf1(b) << 16);
}

__device__ inline void load_lds16(const void* g, void* l) {
  __builtin_amdgcn_global_load_lds(
      (const __attribute__((address_space(1))) uint32_t*)g,
      (__attribute__((address_space(3))) uint32_t*)l, 16, 0, 0);
}

// ---- merged: blocks 0..255 normalize K (64 keys) -> Kn + KnT;
//      blocks 256..1279 normalize Q (4 rows) -> Qn, and init out = Q --------
__global__ void norm_qk_kernel(const float* __restrict__ q,
                               const float* __restrict__ k,
                               float* __restrict__ out,
                               unsigned short* __restrict__ Qn,
                               unsigned short* __restrict__ Kn,
                               unsigned short* __restrict__ KnT) {
  __shared__ unsigned short tile[64 * KROW];
  const int wave = threadIdx.x >> 6, lane = threadIdx.x & 63;

  if (blockIdx.x >= 256) {               // ---- Q path ----
    const int row = (blockIdx.x - 256) * 4 + wave;
    const float4* qr = (const float4*)(q + (size_t)row * D);
    float4 a = qr[lane * 2];
    float4 b = qr[lane * 2 + 1];
    float ss = a.x*a.x + a.y*a.y + a.z*a.z + a.w*a.w
             + b.x*b.x + b.y*b.y + b.z*b.z + b.w*b.w;
#pragma unroll
    for (int m = 32; m >= 1; m >>= 1) ss += __shfl_xor(ss, m, 64);
    const float sc = 1.0f / fmaxf(sqrtf(ss), 1e-12f);
    float4* orow = (float4*)(out + (size_t)row * D);
    orow[lane * 2]     = a;
    orow[lane * 2 + 1] = b;
    uint4v w;
    w.x = pack2(a.x*sc, a.y*sc); w.y = pack2(a.z*sc, a.w*sc);
    w.z = pack2(b.x*sc, b.y*sc); w.w = pack2(b.z*sc, b.w*sc);
    *(uint4v*)(Qn + (size_t)row * D + lane * 8) = w;
    return;
  }
  // ---- K path (R5-verified 256-thread body) ----
  const int n0 = blockIdx.x * 64;
#pragma unroll 1
  for (int i = 0; i < 16; ++i) {
    const int rl = wave * 16 + i;
    const int n  = n0 + rl;
    const float4* kr = (const float4*)(k + (size_t)n * D);
    float4 a = kr[lane * 2], b = kr[lane * 2 + 1];
    float ss = a.x*a.x + a.y*a.y + a.z*a.z + a.w*a.w
             + b.x*b.x + b.y*b.y + b.z*b.z + b.w*b.w;
#pragma unroll
    for (int m = 32; m >= 1; m >>= 1) ss += __shfl_xor(ss, m, 64);
    const float sc = 1.0f / fmaxf(sqrtf(ss), 1e-12f);
    uint4v w;
    w.x = pack2(a.x*sc, a.y*sc); w.y = pack2(a.z*sc, a.w*sc);
    w.z = pack2(b.x*sc, b.y*sc); w.w = pack2(b.z*sc, b.w*sc);
    *(uint4v*)(Kn + (size_t)n * D + lane * 8) = w;
    *(uint4v*)&tile[rl * KROW + lane * 8]     = w;
  }
  __syncthreads();
  const int dsub = threadIdx.x >> 3;        // 0..31
  const int nl   = (threadIdx.x & 7) * 8;   // 0..56
#pragma unroll 1
  for (int iter = 0; iter < 16; ++iter) {
    const int d = iter * 32 + dsub;
    uint4v w;
    w.x = (uint32_t)tile[(nl+0)*KROW + d] | ((uint32_t)tile[(nl+1)*KROW + d] << 16);
    w.y = (uint32_t)tile[(nl+2)*KROW + d] | ((uint32_t)tile[(nl+3)*KROW + d] << 16);
    w.z = (uint32_t)tile[(nl+4)*KROW + d] | ((uint32_t)tile[(nl+5)*KROW + d] << 16);
    w.w = (uint32_t)tile[(nl+6)*KROW + d] | ((uint32_t)tile[(nl+7)*KROW + d] << 16);
    *(uint4v*)(KnT + (size_t)d * NK + n0 + nl) = w;
  }
}

// ---------------- fused: S = Qn Kn^T chunk, P = exp, O += P Kn --------------
// R10 cross-barrier pipeline + R7's 32x32x16 kh-split GEMM1 (halves the
// dominant LDS b128 volume: 256 -> 128 reads/chunk). P single-buffered
// (barA separates GEMM2(c) from exp(c+1)) so K-dbuf+P+Sred = 158.7KB fits.
// All staging/ktf loads cross >= 2 barriers (a full GEMM1 phase) before use.
__global__ __launch_bounds__(512, 2) void fused_kernel(
    const unsigned short* __restrict__ Qn,
    const unsigned short* __restrict__ Kn,
    const unsigned short* __restrict__ KnT,
    float* __restrict__ out) {
  __shared__ unsigned short K_lds[2][BN * KROW];   // 133120 B
  __shared__ unsigned short P_lds[BQ * PROW];      //   9216 B
  __shared__ float Sred[4][32 * 32];               //  16384 B  = 158.7 KB

  const int tid  = threadIdx.x;
  const int wave = tid >> 6, lane = tid & 63;
  const int l15  = lane & 15, quad = lane >> 4;
  const int l31  = lane & 31, half = lane >> 5;
  const int nsplit = blockIdx.x & (NSPLIT - 1);
  const int qtile  = blockIdx.x >> 2;           // 0..63
  const int q0     = qtile * BQ;
  const int nbase  = nsplit * NRANGE;
  // GEMM1 roles (R7-verified): S^T tile (nt2, qt2), D-half kh
  const int nt2 = wave & 1, qt2 = (wave >> 1) & 1, kh = wave >> 2;
  const int g1tile = nt2 * 2 + qt2;

  // GEMM1 B-frags (Q): B[k=16][n=32q], n=l31, k=half*8+j; this kh half (64 VGPR)
  short8 qfB[16];
  {
    const unsigned short* qrow = Qn + (size_t)(q0 + qt2*32 + l31) * D
                                 + kh * 256 + half * 8;
#pragma unroll
    for (int ks = 0; ks < 16; ++ks) qfB[ks] = *(const short8*)(qrow + ks * 16);
  }

  floatx4 oacc[4][4] = {};   // wave's 64q x 64d O slice (d cols wave*64..+63)
  short8 ktf[2][4];          // GEMM2 B-frags (32 VGPR), single-buffered

  const unsigned short* ktrow = KnT + (size_t)(wave*64 + l15) * NK + nbase + quad*8;

  auto stage = [&](int ch, int buf) {
#pragma unroll
    for (int i = 0; i < 8; ++i) {
      const int row = wave * 8 + i;
      load_lds16(Kn + (size_t)(nbase + ch*BN + row) * D + lane * 8,
                 &K_lds[buf][row * KROW]);
    }
  };
  auto ktf_load = [&](int ch) {
#pragma unroll
    for (int kb2 = 0; kb2 < 2; ++kb2)
#pragma unroll
      for (int td = 0; td < 4; ++td)
        ktf[kb2][td] = *(const short8*)(ktrow + (size_t)td*16*NK + ch*BN + kb2*32);
  };
  auto gemm1 = [&](int buf, floatx16& s) {
    const unsigned short* abase =
        &K_lds[buf][(nt2*32 + l31) * KROW + kh * 256 + half * 8];
#pragma unroll
    for (int ks = 0; ks < 16; ++ks) {
      short8 a = *(const short8*)(abase + ks * 16);
      s = __builtin_amdgcn_mfma_f32_32x32x16_bf16(a, qfB[ks], s, 0, 0, 0);
    }
  };
  auto sred_export = [&](const floatx16& s) {   // kh==1 waves
    float* sr = &Sred[g1tile][lane * 16];
#pragma unroll
    for (int g = 0; g < 4; ++g) {
      float4 v = { s[4*g], s[4*g+1], s[4*g+2], s[4*g+3] };
      ((float4*)sr)[g] = v;
    }
  };
  auto exp_pw = [&](const floatx16& s) {        // kh==0 waves
    const float* sr = &Sred[g1tile][lane * 16];
    const int q = qt2 * 32 + l31;
#pragma unroll
    for (int g = 0; g < 4; ++g) {
      float4 r = ((const float4*)sr)[g];
      float e0 = __expf(BETA * (s[4*g+0] + r.x - 1.f));
      float e1 = __expf(BETA * (s[4*g+1] + r.y - 1.f));
      float e2 = __expf(BETA * (s[4*g+2] + r.z - 1.f));
      float e3 = __expf(BETA * (s[4*g+3] + r.w - 1.f));
      uint2v w; w.x = pack2(e0, e1); w.y = pack2(e2, e3);
      // keys for regs 4g..4g+3: nt2*32 + g*8 + half*4 + {0..3}
      *(uint2v*)&P_lds[q * PROW + nt2*32 + g*8 + half*4] = w;
    }
  };
  auto gemm2 = [&]() {
#pragma unroll
    for (int kb2 = 0; kb2 < 2; ++kb2) {
      short8 pf[4];
#pragma unroll
      for (int tr = 0; tr < 4; ++tr)
        pf[tr] = *(const short8*)&P_lds[(tr*16 + l15) * PROW + kb2*32 + quad*8];
#pragma unroll
      for (int td = 0; td < 4; ++td)
#pragma unroll
        for (int tr = 0; tr < 4; ++tr)
          oacc[tr][td] = __builtin_amdgcn_mfma_f32_16x16x32_bf16(
              pf[tr], ktf[kb2][td], oacc[tr][td], 0, 0, 0);
    }
  };

  // ---- prologue
  stage(0, 0);
  ktf_load(0);
  __syncthreads();                       // staging(0) drained
  stage(1, 1);
  {
    floatx16 s = {};
    gemm1(0, s);
    if (kh == 1) sred_export(s);
    __syncthreads();                     // barA(0): Sred(0) visible; stage(1) drained
    if (kh == 0) exp_pw(s);
  }
  __syncthreads();                       // barB(0): P(0) visible

  // ---- steady loop: iter c does GEMM2(c) + GEMM1(c+1) + stage(c+2)
#pragma unroll 1
  for (int c = 0; c < CHUNKS; ++c) {
    gemm2();                             // consumes P(c), ktf(c)
    if (c + 1 < CHUNKS) ktf_load(c + 1); // drained by barA/barB below
    if (c + 2 < CHUNKS) stage(c + 2, c & 1);   // K_lds[c&1] free since barB(c-1)
    floatx16 s = {};
    if (c + 1 < CHUNKS) {
      gemm1((c + 1) & 1, s);
      if (kh == 1) sred_export(s);
    }
    __syncthreads();                     // barA: Sred(c+1) visible; GEMM2(c) done
    if (c + 1 < CHUNKS && kh == 0) exp_pw(s);
    __syncthreads();                     // barB: P(c+1) visible; staging drained
  }

  // ---- epilogue: out += ALPHA * O (out pre-init to Q; atomics L2-coalesce)
  const int colbase = wave * 64 + l15;
#pragma unroll
  for (int tr = 0; tr < 4; ++tr)
#pragma unroll
    for (int td = 0; td < 4; ++td)
#pragma unroll
      for (int r = 0; r < 4; ++r)
        atomicAdd(out + (size_t)(q0 + tr*16 + quad*4 + r) * D + colbase + td*16,
                  ALPHA * oacc[tr][td][r]);
}

extern "C" void kernel_launch(void* const* d_in, const int* in_sizes, int n_in,
                              void* d_out, int out_size, void* d_ws, size_t ws_size,
                              hipStream_t stream) {
  (void)in_sizes; (void)n_in; (void)out_size; (void)ws_size;
  const float* q = (const float*)d_in[0];
  const float* k = (const float*)d_in[1];
  float* out = (float*)d_out;
  unsigned short* Qn  = (unsigned short*)d_ws;          //  4 MB
  unsigned short* Kn  = Qn + (size_t)NB * D;            // 16 MB
  unsigned short* KnT = Kn + (size_t)NK * D;            // 16 MB  (total 36 MB)

  hipLaunchKernelGGL(norm_qk_kernel, dim3(256 + NB / 4), dim3(256), 0, stream,
                     q, k, out, Qn, Kn, KnT);
  hipLaunchKernelGGL(fused_kernel, dim3((NB / BQ) * NSPLIT), dim3(512), 0, stream,
                     Qn, Kn, KnT, out);
}